// Round 16
// baseline (159.262 us; speedup 1.0000x reference)
//
#include <hip/hip_runtime.h>
#include <hip/hip_bf16.h>
#include <math.h>

// Problem constants
#define BT    96          // B*T = 8*12
#define NSEQ  512         // N
#define DMODEL 64         // D = K*d
#define RTOT  (BT * NSEQ) // 49152 rows

// Workspace layout (floats). Q/K/V planes hold PACKED SPLIT-BF16 u32
// (hi | lo<<16) per element, head-major [head][row][8]; O is fp32
// head-major. Offsets unchanged in size.
#define QOFF  0
#define KOFF  ((size_t)RTOT * DMODEL)
#define VOFF  ((size_t)2 * RTOT * DMODEL)
#define OOFF  ((size_t)3 * RTOT * DMODEL)
#define WOFF  ((size_t)4 * RTOT * DMODEL)   // W-fragment cache (128 KB)

#define HPLANE ((size_t)RTOT * 8)           // elems per head plane

// Guaranteed single-instruction 2^x / 1/x.
static __device__ inline float fast_exp2(float x) {
#if __has_builtin(__builtin_amdgcn_exp2f)
    return __builtin_amdgcn_exp2f(x);
#else
    float r; asm("v_exp_f32 %0, %1" : "=v"(r) : "v"(x)); return r;
#endif
}
static __device__ inline float fast_rcp(float x) {
#if __has_builtin(__builtin_amdgcn_rcpf)
    return __builtin_amdgcn_rcpf(x);
#else
    return 1.f / x;
#endif
}

typedef __attribute__((ext_vector_type(8)))  short short8;
typedef __attribute__((ext_vector_type(16))) float float16v;

static __device__ inline short8 as_s8(uint4 u) {
    union { uint4 u; short8 s; } x; x.u = u; return x.s;
}

static __device__ inline uint32_t bf162_bits(__hip_bfloat162 h) {
    union { __hip_bfloat162 h; uint32_t u; } x; x.h = h; return x.u;
}

// Split 8 fp32 into packed bf16 hi (RNE) + bf16 lo (exact residual, RNE).
static __device__ inline void split_pack8(const float* v, uint4* hi, uint4* lo) {
    uint32_t h[4], l[4];
    #pragma unroll
    for (int t = 0; t < 4; ++t) {
        float x0 = v[2 * t], x1 = v[2 * t + 1];
        uint32_t hw = bf162_bits(__float22bfloat162_rn(make_float2(x0, x1)));
        float h0 = __uint_as_float(hw << 16);
        float h1 = __uint_as_float(hw & 0xffff0000u);
        h[t] = hw;
        float l0 = x0 - h0;
        float l1 = x1 - h1;
        l[t] = bf162_bits(__float22bfloat162_rn(make_float2(l0, l1)));
    }
    *hi = make_uint4(h[0], h[1], h[2], h[3]);
    *lo = make_uint4(l[0], l[1], l[2], l[3]);
}

// Hi-only pack: 8 fp32 -> packed bf16 (RNE). 4 VALU ops (vs 24 for split).
static __device__ inline uint4 pack_hi8(const float* v) {
    uint32_t h[4];
    #pragma unroll
    for (int t = 0; t < 4; ++t)
        h[t] = bf162_bits(__float22bfloat162_rn(make_float2(v[2 * t], v[2 * t + 1])));
    return make_uint4(h[0], h[1], h[2], h[3]);
}

// Repack two split-u32 (hi|lo<<16) into bf162 words: 1 v_perm_b32 each.
static __device__ inline uint32_t perm_hi(uint32_t pa, uint32_t pb) {
#if __has_builtin(__builtin_amdgcn_perm)
    return __builtin_amdgcn_perm(pb, pa, 0x05040100u);  // {pa.b0,pa.b1,pb.b0,pb.b1}
#else
    return (pa & 0xFFFFu) | (pb << 16);
#endif
}
static __device__ inline uint32_t perm_lo(uint32_t pa, uint32_t pb) {
#if __has_builtin(__builtin_amdgcn_perm)
    return __builtin_amdgcn_perm(pb, pa, 0x07060302u);  // {pa.b2,pa.b3,pb.b2,pb.b3}
#else
    return (pa >> 16) | (pb & 0xFFFF0000u);
#endif
}
static __device__ inline uint4 hi4_of(uint4 p0, uint4 p1) {
    return make_uint4(perm_hi(p0.x, p0.y), perm_hi(p0.z, p0.w),
                      perm_hi(p1.x, p1.y), perm_hi(p1.z, p1.w));
}
static __device__ inline uint4 lo4_of(uint4 p0, uint4 p1) {
    return make_uint4(perm_lo(p0.x, p0.y), perm_lo(p0.z, p0.w),
                      perm_lo(p1.x, p1.y), perm_lo(p1.z, p1.w));
}

// ---------------------------------------------------------------------------
// Kernel 0: pre-split W7/8/9 (K=128) and W10/W11 (K=64) into bf16 hi/lo
// B-fragment layout. [0,3072) = W789; [3072,3584) = W10; [3584,4096) = W11.
// ---------------------------------------------------------------------------
__global__ __launch_bounds__(256) void wprep_kernel(
    const float* __restrict__ W7, const float* __restrict__ W8,
    const float* __restrict__ W9, const float* __restrict__ W10,
    const float* __restrict__ W11,
    uint4* __restrict__ WfH, uint4* __restrict__ WfL)
{
    const int e = blockIdx.x * 256 + threadIdx.x;   // 0..4095
    const float* W;
    int k0, col;
    if (e < 3072) {
        int n  = e & 31;
        int t  = (e >> 5) & 1;
        int hh = (e >> 6) & 1;
        int c  = (e >> 7) & 7;
        int w  = e >> 10;
        W = (w == 0) ? W7 : (w == 1) ? W8 : W9;
        k0 = c * 16 + hh * 8;
        col = t * 32 + n;
    } else {
        int pe = e - 3072;
        int n  = pe & 31;
        int t  = (pe >> 5) & 1;
        int hh = (pe >> 6) & 1;
        int c  = (pe >> 7) & 3;
        int m  = pe >> 9;
        W = (m == 0) ? W10 : W11;
        k0 = c * 16 + hh * 8;
        col = t * 32 + n;
    }
    float v[8];
    #pragma unroll
    for (int j = 0; j < 8; ++j) v[j] = W[(size_t)(k0 + j) * 64 + col];
    uint4 hi, lo;
    split_pack8(v, &hi, &lo);
    WfH[e] = hi;
    WfL[e] = lo;
}

// ---------------------------------------------------------------------------
// Kernel 1 (R22): fused-W QKV = R14 two-phase staging (R10-measured-best;
// W-hoist reverted, it was null/-2us). Epilogue now SPLITS AND STORES
// packed (hi|lo<<16) u32 per element — identical __float22bfloat162_rn
// primitive on identical fp32 values as attn's old staging split (Q plane
// pre-scaled by C) -> bitwise-identical pipeline output; attn's staging
// re-split is replaced by 1-op perm repacks.
// ---------------------------------------------------------------------------
__global__ __launch_bounds__(384) void qkv_kernel(
    const float* __restrict__ X, const float* __restrict__ STE,
    const uint4* __restrict__ WfH, const uint4* __restrict__ WfL,
    const float* __restrict__ b7, const float* __restrict__ b8,
    const float* __restrict__ b9,
    float* __restrict__ qkv)
{
    __shared__ float Xs[32][132];  // 16.9 KB raw [X|STE] rows (pad vs conflicts)
    __shared__ uint4 aH[512];      // 8 KB: A_hi frags, entry = c*64 + hh*32 + l31
    __shared__ uint4 aL[512];      // 8 KB: A_lo frags

    const int tid  = threadIdx.x;
    const int l31  = tid & 31;
    const int hh   = (tid >> 5) & 1;
    const int wave = tid >> 6;              // 0..5
    const int w    = wave >> 1;             // 0,1,2 -> W7,W8,W9
    const int tt   = wave & 1;              // column half
    const size_t blockrow = (size_t)blockIdx.x * 32;

    // Phase 1: coalesced raw stage. 1024 float4s: row = e>>5, seg = e&31.
    for (int e = tid; e < 1024; e += 384) {
        const int row = e >> 5;
        const int seg = e & 31;
        const float* src = (seg < 16) ? X : STE;
        const float4 v = *(const float4*)(src + (blockrow + row) * 64 + (seg & 15) * 4);
        float* dst = &Xs[row][seg * 4];
        dst[0] = v.x; dst[1] = v.y; dst[2] = v.z; dst[3] = v.w;
    }
    __syncthreads();

    // Phase 2: build split frags from LDS (split once, consumed by 6 waves).
    for (int e = tid; e < 512; e += 384) {
        const int el  = e & 31;
        const int ehh = (e >> 5) & 1;
        const int ec  = e >> 6;
        const float* hp = &Xs[el][ec * 16 + ehh * 8];
        float av[8];
        #pragma unroll
        for (int j = 0; j < 8; ++j) av[j] = hp[j];
        uint4 hi, lo;
        split_pack8(av, &hi, &lo);
        aH[e] = hi;
        aL[e] = lo;
    }
    __syncthreads();

    float16v accM, accC;
    #pragma unroll
    for (int i = 0; i < 16; ++i) { accM[i] = 0.f; accC[i] = 0.f; }

    #pragma unroll
    for (int c = 0; c < 8; ++c) {
        const uint4 ahi = aH[c * 64 + hh * 32 + l31];
        const uint4 alo = aL[c * 64 + hh * 32 + l31];
        const int ei = w * 1024 + c * 128 + hh * 64 + tt * 32 + l31;
        const uint4 bh = WfH[ei];
        const uint4 bl = WfL[ei];
        accM = __builtin_amdgcn_mfma_f32_32x32x16_bf16(
            as_s8(ahi), as_s8(bh), accM, 0, 0, 0);
        accC = __builtin_amdgcn_mfma_f32_32x32x16_bf16(
            as_s8(alo), as_s8(bh), accC, 0, 0, 0);
        accC = __builtin_amdgcn_mfma_f32_32x32x16_bf16(
            as_s8(ahi), as_s8(bl), accC, 0, 0, 0);
    }

    const float* bv = (w == 0) ? b7 : (w == 1) ? b8 : b9;
    // Head-major store: col = tt*32+l31 = head*8 + d.
    const int head = tt * 4 + (l31 >> 3);
    const int d    = l31 & 7;
    const int col  = tt * 32 + l31;
    uint32_t* obase = (uint32_t*)qkv + (size_t)w * ((size_t)RTOT * DMODEL)
                      + (size_t)head * HPLANE;
    const float bias = bv[col];
    const float cs = (w == 0) ? 0.51012091684045906f : 1.0f;  // Q pre-scale
    #pragma unroll
    for (int r = 0; r < 16; r += 2) {
        const int rowC0 = (r & 3) + 8 * (r >> 2) + 4 * hh;
        const int rowC1 = ((r + 1) & 3) + 8 * ((r + 1) >> 2) + 4 * hh;
        const float v0 = fmaxf(accM[r]     + accC[r]     + bias, 0.f) * cs;
        const float v1 = fmaxf(accM[r + 1] + accC[r + 1] + bias, 0.f) * cs;
        const uint32_t hw = bf162_bits(__float22bfloat162_rn(make_float2(v0, v1)));
        const float h0 = __uint_as_float(hw << 16);
        const float h1 = __uint_as_float(hw & 0xffff0000u);
        const uint32_t lw = bf162_bits(
            __float22bfloat162_rn(make_float2(v0 - h0, v1 - h1)));
        obase[(blockrow + rowC0) * 8 + d] = (hw & 0xFFFFu) | (lw << 16);
        obase[(blockrow + rowC1) * 8 + d] = (hw >> 16) | (lw & 0xFFFF0000u);
    }
}

// ---------------------------------------------------------------------------
// Kernel 2 (R22): attention, 768 x 1024 threads (R17 shape, measured
// 47.4-48.0; both neighbors regressed). Staging now loads packed split-u32
// and repacks with v_perm (1 op/word, was 24-op split_pack8 per 8 elems);
// Q-scale moved to qkv. Main loop unchanged (hi-only P, Sa/Sb pipeline).
// ---------------------------------------------------------------------------
__global__ __launch_bounds__(1024) void attn_kernel(
    const float* __restrict__ qkv, float* __restrict__ obuf)
{
    __shared__ uint4 ak1[16 * 32];    //  8.0 KB  k_hi
    __shared__ uint4 ak2p[16 * 33];   //  8.3 KB  k_lo | zero column
    __shared__ uint4 vfh[640];        // 10.0 KB  V_hi frags (+zero pad)
    __shared__ uint4 vfl[640];        // 10.0 KB  V_lo frags (+zero pad)

    const int tid  = threadIdx.x;
    const int lane = tid & 63;
    const int l31  = lane & 31;
    const int hh   = lane >> 5;
    const int qt   = tid >> 6;               // 0..15: this wave's q-tile
    const int head = blockIdx.x & 7;
    const int bt   = blockIdx.x >> 3;

    // Head-major base: plane 'head', rows bt*512..bt*512+511, 8 elems/row.
    const size_t hb = (size_t)head * HPLANE + (size_t)bt * (NSEQ * 8);
    const uint32_t* Qp = (const uint32_t*)qkv + QOFF + hb;
    const uint32_t* Kp = (const uint32_t*)qkv + KOFF + hb;
    const uint32_t* Vp = (const uint32_t*)qkv + VOFF + hb;

    const uint4 z4 = make_uint4(0, 0, 0, 0);

    // K staging: threads 0..511, contiguous 32B rows; perm-repack.
    if (tid < 512) {
        const int k = tid;
        const uint32_t* kr = Kp + (size_t)k * 8;
        const uint4 p0 = *(const uint4*)(kr);
        const uint4 p1 = *(const uint4*)(kr + 4);
        ak1[k] = hi4_of(p0, p1);
        ak2p[(k >> 5) * 33 + (k & 31)] = lo4_of(p0, p1);
    }
    if (tid < 16) ak2p[tid * 33 + 32] = z4;

    // V-frag build: threads 0..639 (global gather; perm-repack).
    if (tid < 640) {
        const int e = tid;
        if (e < 576) {
            int s  = e / 18;
            int r  = e % 18;
            int hv = r / 9;
            int n  = r % 9;
            uint32_t p[8];
            #pragma unroll
            for (int j = 0; j < 8; ++j) {
                int key = 16 * s + ((j < 4) ? (4 * hv + j) : (8 + 4 * hv + (j - 4)));
                p[j] = (n < 8) ? Vp[(size_t)key * 8 + n] : 0x00003F80u;  // split(1.0f)
            }
            vfh[e] = make_uint4(perm_hi(p[0], p[1]), perm_hi(p[2], p[3]),
                                perm_hi(p[4], p[5]), perm_hi(p[6], p[7]));
            vfl[e] = make_uint4(perm_lo(p[0], p[1]), perm_lo(p[2], p[3]),
                                perm_lo(p[4], p[5]), perm_lo(p[6], p[7]));
        } else {
            vfh[e] = z4;
            vfl[e] = z4;
        }
    }

    __syncthreads();

    const int idx2 = hh ? 32 : l31;        // zero column for hh=1 lanes

    float16v Z16;
    #pragma unroll
    for (int i = 0; i < 16; ++i) Z16[i] = 0.f;

    {
        // Q fragment: pre-scaled + pre-split in qkv; perm-repack only.
        const uint32_t* qp = Qp + (size_t)(qt * 32 + l31) * 8;
        const uint4 p0 = *(const uint4*)(qp);
        const uint4 p1 = *(const uint4*)(qp + 4);
        const uint4 qhi = hi4_of(p0, p1);
        const uint4 qlo = lo4_of(p0, p1);
        const uint4 bq1 = hh ? qlo : qhi;
        const uint4 bq2 = qhi;

        float16v O = Z16;

        // Prologue: S for c=0.
        float16v Sa, Sb;
        {
            const uint4 a1 = ak1[l31];
            const uint4 a2 = ak2p[idx2];
            Sa = __builtin_amdgcn_mfma_f32_32x32x16_bf16(as_s8(a1), as_s8(bq1), Z16, 0, 0, 0);
            Sa = __builtin_amdgcn_mfma_f32_32x32x16_bf16(as_s8(a2), as_s8(bq2), Sa, 0, 0, 0);
        }

        // One pipelined step: consume Scur (exp/pack-hi/O-MFMA) while issuing
        // the S-MFMAs for iteration cn into Snext.
#define ATTN_STEP(Scur, Snext, cc, cn)                                         \
        {                                                                      \
            const int vi0 = (4 * (cc) + hh) * 9;                               \
            const int vi1 = (4 * (cc) + 2 + hh) * 9;                           \
            const uint4 bh0 = vfh[vi0 + l31];                                  \
            const uint4 bl0 = vfl[vi0 + l31];                                  \
            const uint4 bh1 = vfh[vi1 + l31];                                  \
            const uint4 bl1 = vfl[vi1 + l31];                                  \
            const uint4 a1n = ak1[(cn) * 32 + l31];                            \
            const uint4 a2n = ak2p[(cn) * 33 + idx2];                          \
            Snext = __builtin_amdgcn_mfma_f32_32x32x16_bf16(                   \
                as_s8(a1n), as_s8(bq1), Z16, 0, 0, 0);                         \
            Snext = __builtin_amdgcn_mfma_f32_32x32x16_bf16(                   \
                as_s8(a2n), as_s8(bq2), Snext, 0, 0, 0);                       \
            _Pragma("unroll")                                                  \
            for (int i = 0; i < 16; ++i) Scur[i] = fast_exp2(Scur[i]);         \
            const uint4 ph0 = pack_hi8((const float*)&Scur);                   \
            const uint4 ph1 = pack_hi8(((const float*)&Scur) + 8);             \
            O = __builtin_amdgcn_mfma_f32_32x32x16_bf16(                       \
                as_s8(ph0), as_s8(bh0), O, 0, 0, 0);                           \
            O = __builtin_amdgcn_mfma_f32_32x32x16_bf16(                       \
                as_s8(ph0), as_s8(bl0), O, 0, 0, 0);                           \
            O = __builtin_amdgcn_mfma_f32_32x32x16_bf16(                       \
                as_s8(ph1), as_s8(bh1), O, 0, 0, 0);                           \
            O = __builtin_amdgcn_mfma_f32_32x32x16_bf16(                       \
                as_s8(ph1), as_s8(bl1), O, 0, 0, 0);                           \
        }

        for (int c = 0; c < 16; c += 2) {
            ATTN_STEP(Sa, Sb, c, c + 1);
            ATTN_STEP(Sb, Sa, c + 1, (c + 2) & 15);  // last prefetch discarded
        }
#undef ATTN_STEP

        #pragma unroll
        for (int r = 0; r < 16; ++r) {
            float ov = O[r];
            float den = __uint_as_float(
                __builtin_amdgcn_ds_swizzle(__float_as_uint(ov), 0x100));
            float o = ov * fast_rcp(den);
            if (l31 < 8) {
                int row = (r & 3) + 8 * (r >> 2) + 4 * hh;
                obuf[hb + (size_t)(qt * 32 + row) * 8 + l31] = o;
            }
        }
    }
}

// ---------------------------------------------------------------------------
// Kernel 3 (R13 exact, R10-measured-best; W-hoist reverted): fused
// projection; Ts padded to 84.
// ---------------------------------------------------------------------------
__global__ __launch_bounds__(128) void proj_kernel(
    const float* __restrict__ obuf,
    const uint4* __restrict__ WfH, const uint4* __restrict__ WfL,
    const float* __restrict__ b10, const float* __restrict__ b11,
    float* __restrict__ out)
{
    __shared__ float Ts[32][84];

    const int tid  = threadIdx.x;
    const int lane = tid & 63;
    const int l31  = lane & 31;
    const int hh   = lane >> 5;
    const int tw   = tid >> 6;               // 0/1: column half this wave owns
    const size_t row = (size_t)blockIdx.x * 32 + l31;
    const size_t blockrow = (size_t)blockIdx.x * 32;

    float16v accM, accC;
    #pragma unroll
    for (int i = 0; i < 16; ++i) { accM[i] = 0.f; accC[i] = 0.f; }

    #pragma unroll
    for (int c = 0; c < 4; ++c) {
        // A-frag cols c*16+hh*8..+7 = head plane 2c+hh, contiguous row.
        const float* ap = obuf + (size_t)(2 * c + hh) * HPLANE + row * 8;
        float av[8];
        {
            float4 a0 = *(const float4*)(ap);
            float4 a1 = *(const float4*)(ap + 4);
            av[0] = a0.x; av[1] = a0.y; av[2] = a0.z; av[3] = a0.w;
            av[4] = a1.x; av[5] = a1.y; av[6] = a1.z; av[7] = a1.w;
        }
        uint4 ahi, alo;
        split_pack8(av, &ahi, &alo);

        const int ei = 3072 + c * 128 + hh * 64 + tw * 32 + l31;   // W10
        const uint4 bh = WfH[ei];
        const uint4 bl = WfL[ei];
        accM = __builtin_amdgcn_mfma_f32_32x32x16_bf16(
            as_s8(ahi), as_s8(bh), accM, 0, 0, 0);
        accC = __builtin_amdgcn_mfma_f32_32x32x16_bf16(
            as_s8(alo), as_s8(bh), accC, 0, 0, 0);
        accC = __builtin_amdgcn_mfma_f32_32x32x16_bf16(
            as_s8(ahi), as_s8(bl), accC, 0, 0, 0);
    }

    {
        const int col = tw * 32 + l31;
        const float bias = b10[col];
        #pragma unroll
        for (int r = 0; r < 16; ++r) {
            const int rowC = (r & 3) + 8 * (r >> 2) + 4 * hh;
            Ts[rowC][col] = fmaxf(accM[r] + accC[r] + bias, 0.f);
        }
    }
    __syncthreads();

    #pragma unroll
    for (int i = 0; i < 16; ++i) { accM[i] = 0.f; accC[i] = 0.f; }

    #pragma unroll
    for (int c = 0; c < 4; ++c) {
        const float* ap = &Ts[l31][c * 16 + hh * 8];
        float av[8];
        {
            float4 a0 = *(const float4*)(ap);
            float4 a1 = *(const float4*)(ap + 4);
            av[0] = a0.x; av[1] = a0.y; av[2] = a0.z; av[3] = a0.w;
            av[4] = a1.x; av[5] = a1.y; av[6] = a1.z; av[7] = a1.w;
        }
        uint4 ahi, alo;
        split_pack8(av, &ahi, &alo);

        const int ei = 3584 + c * 128 + hh * 64 + tw * 32 + l31;   // W11
        const uint4 bh = WfH[ei];
        const uint4 bl = WfL[ei];
        accM = __builtin_amdgcn_mfma_f32_32x32x16_bf16(
            as_s8(ahi), as_s8(bh), accM, 0, 0, 0);
        accC = __builtin_amdgcn_mfma_f32_32x32x16_bf16(
            as_s8(alo), as_s8(bh), accC, 0, 0, 0);
        accC = __builtin_amdgcn_mfma_f32_32x32x16_bf16(
            as_s8(ahi), as_s8(bl), accC, 0, 0, 0);
    }

    {
        const int col = tw * 32 + l31;
        const float bias = b11[col];
        #pragma unroll
        for (int r = 0; r < 16; ++r) {
            const int rowC = (r & 3) + 8 * (r >> 2) + 4 * hh;
            out[(blockrow + rowC) * 64 + col] = accM[r] + accC[r] + bias;
        }
    }
}

// ---------------------------------------------------------------------------
extern "C" void kernel_launch(void* const* d_in, const int* in_sizes, int n_in,
                              void* d_out, int out_size, void* d_ws, size_t ws_size,
                              hipStream_t stream)
{
    const float* X   = (const float*)d_in[0];
    const float* STE = (const float*)d_in[1];
    const float* W7  = (const float*)d_in[2];
    const float* b7  = (const float*)d_in[3];
    const float* W8  = (const float*)d_in[4];
    const float* b8  = (const float*)d_in[5];
    const float* W9  = (const float*)d_in[6];
    const float* b9  = (const float*)d_in[7];
    const float* W10 = (const float*)d_in[8];
    const float* b10 = (const float*)d_in[9];
    const float* W11 = (const float*)d_in[10];
    const float* b11 = (const float*)d_in[11];

    float* ws  = (float*)d_ws;   // Q | K | V | O | Wf
    float* out = (float*)d_out;

    uint4* WfH = (uint4*)(ws + WOFF);
    uint4* WfL = WfH + 4096;

    wprep_kernel<<<dim3(16), 256, 0, stream>>>(W7, W8, W9, W10, W11, WfH, WfL);
    qkv_kernel<<<dim3(RTOT / 32), 384, 0, stream>>>(X, STE, WfH, WfL, b7, b8, b9, ws);
    attn_kernel<<<dim3(BT * 8), 1024, 0, stream>>>(ws, ws + OOFF);
    proj_kernel<<<dim3(RTOT / 32), 128, 0, stream>>>(ws + OOFF, WfH, WfL, b10, b11, out);
}

// Round 17
// 156.821 us; speedup vs baseline: 1.0156x; 1.0156x over previous
//
#include <hip/hip_runtime.h>
#include <hip/hip_bf16.h>
#include <math.h>

// Problem constants
#define BT    96          // B*T = 8*12
#define NSEQ  512         // N
#define DMODEL 64         // D = K*d
#define RTOT  (BT * NSEQ) // 49152 rows

// Workspace layout (floats). Q/K/V AND O planes hold PACKED SPLIT-BF16 u32
// (hi | lo<<16) per element, head-major [head][row][8]. Offsets unchanged.
#define QOFF  0
#define KOFF  ((size_t)RTOT * DMODEL)
#define VOFF  ((size_t)2 * RTOT * DMODEL)
#define OOFF  ((size_t)3 * RTOT * DMODEL)
#define WOFF  ((size_t)4 * RTOT * DMODEL)   // W-fragment cache (128 KB)

#define HPLANE ((size_t)RTOT * 8)           // elems per head plane

// Guaranteed single-instruction 2^x / 1/x.
static __device__ inline float fast_exp2(float x) {
#if __has_builtin(__builtin_amdgcn_exp2f)
    return __builtin_amdgcn_exp2f(x);
#else
    float r; asm("v_exp_f32 %0, %1" : "=v"(r) : "v"(x)); return r;
#endif
}
static __device__ inline float fast_rcp(float x) {
#if __has_builtin(__builtin_amdgcn_rcpf)
    return __builtin_amdgcn_rcpf(x);
#else
    return 1.f / x;
#endif
}

typedef __attribute__((ext_vector_type(8)))  short short8;
typedef __attribute__((ext_vector_type(16))) float float16v;

static __device__ inline short8 as_s8(uint4 u) {
    union { uint4 u; short8 s; } x; x.u = u; return x.s;
}

static __device__ inline uint32_t bf162_bits(__hip_bfloat162 h) {
    union { __hip_bfloat162 h; uint32_t u; } x; x.h = h; return x.u;
}

// Split 8 fp32 into packed bf16 hi (RNE) + bf16 lo (exact residual, RNE).
static __device__ inline void split_pack8(const float* v, uint4* hi, uint4* lo) {
    uint32_t h[4], l[4];
    #pragma unroll
    for (int t = 0; t < 4; ++t) {
        float x0 = v[2 * t], x1 = v[2 * t + 1];
        uint32_t hw = bf162_bits(__float22bfloat162_rn(make_float2(x0, x1)));
        float h0 = __uint_as_float(hw << 16);
        float h1 = __uint_as_float(hw & 0xffff0000u);
        h[t] = hw;
        float l0 = x0 - h0;
        float l1 = x1 - h1;
        l[t] = bf162_bits(__float22bfloat162_rn(make_float2(l0, l1)));
    }
    *hi = make_uint4(h[0], h[1], h[2], h[3]);
    *lo = make_uint4(l[0], l[1], l[2], l[3]);
}

// Hi-only pack: 8 fp32 -> packed bf16 (RNE). 4 VALU ops (vs 24 for split).
static __device__ inline uint4 pack_hi8(const float* v) {
    uint32_t h[4];
    #pragma unroll
    for (int t = 0; t < 4; ++t)
        h[t] = bf162_bits(__float22bfloat162_rn(make_float2(v[2 * t], v[2 * t + 1])));
    return make_uint4(h[0], h[1], h[2], h[3]);
}

// Repack two split-u32 (hi|lo<<16) into bf162 words: 1 v_perm_b32 each.
static __device__ inline uint32_t perm_hi(uint32_t pa, uint32_t pb) {
#if __has_builtin(__builtin_amdgcn_perm)
    return __builtin_amdgcn_perm(pb, pa, 0x05040100u);  // {pa.b0,pa.b1,pb.b0,pb.b1}
#else
    return (pa & 0xFFFFu) | (pb << 16);
#endif
}
static __device__ inline uint32_t perm_lo(uint32_t pa, uint32_t pb) {
#if __has_builtin(__builtin_amdgcn_perm)
    return __builtin_amdgcn_perm(pb, pa, 0x07060302u);  // {pa.b2,pa.b3,pb.b2,pb.b3}
#else
    return (pa >> 16) | (pb & 0xFFFF0000u);
#endif
}
static __device__ inline uint4 hi4_of(uint4 p0, uint4 p1) {
    return make_uint4(perm_hi(p0.x, p0.y), perm_hi(p0.z, p0.w),
                      perm_hi(p1.x, p1.y), perm_hi(p1.z, p1.w));
}
static __device__ inline uint4 lo4_of(uint4 p0, uint4 p1) {
    return make_uint4(perm_lo(p0.x, p0.y), perm_lo(p0.z, p0.w),
                      perm_lo(p1.x, p1.y), perm_lo(p1.z, p1.w));
}

// Split a value pair (v0,v1) into one packed-hi word + packed-lo word,
// then interleave into two (hi|lo<<16) u32s.
static __device__ inline void split_store_pair(float v0, float v1,
                                               uint32_t* s0, uint32_t* s1) {
    const uint32_t hw = bf162_bits(__float22bfloat162_rn(make_float2(v0, v1)));
    const float h0 = __uint_as_float(hw << 16);
    const float h1 = __uint_as_float(hw & 0xffff0000u);
    const uint32_t lw = bf162_bits(
        __float22bfloat162_rn(make_float2(v0 - h0, v1 - h1)));
    *s0 = (hw & 0xFFFFu) | (lw << 16);
    *s1 = (hw >> 16) | (lw & 0xFFFF0000u);
}

// ---------------------------------------------------------------------------
// Kernel 0: pre-split W7/8/9 (K=128) and W10/W11 (K=64) into bf16 hi/lo
// B-fragment layout. [0,3072) = W789; [3072,3584) = W10; [3584,4096) = W11.
// ---------------------------------------------------------------------------
__global__ __launch_bounds__(256) void wprep_kernel(
    const float* __restrict__ W7, const float* __restrict__ W8,
    const float* __restrict__ W9, const float* __restrict__ W10,
    const float* __restrict__ W11,
    uint4* __restrict__ WfH, uint4* __restrict__ WfL)
{
    const int e = blockIdx.x * 256 + threadIdx.x;   // 0..4095
    const float* W;
    int k0, col;
    if (e < 3072) {
        int n  = e & 31;
        int t  = (e >> 5) & 1;
        int hh = (e >> 6) & 1;
        int c  = (e >> 7) & 7;
        int w  = e >> 10;
        W = (w == 0) ? W7 : (w == 1) ? W8 : W9;
        k0 = c * 16 + hh * 8;
        col = t * 32 + n;
    } else {
        int pe = e - 3072;
        int n  = pe & 31;
        int t  = (pe >> 5) & 1;
        int hh = (pe >> 6) & 1;
        int c  = (pe >> 7) & 3;
        int m  = pe >> 9;
        W = (m == 0) ? W10 : W11;
        k0 = c * 16 + hh * 8;
        col = t * 32 + n;
    }
    float v[8];
    #pragma unroll
    for (int j = 0; j < 8; ++j) v[j] = W[(size_t)(k0 + j) * 64 + col];
    uint4 hi, lo;
    split_pack8(v, &hi, &lo);
    WfH[e] = hi;
    WfL[e] = lo;
}

// ---------------------------------------------------------------------------
// Kernel 1 (R22, kept): fused-W QKV, two-phase staging; epilogue splits and
// stores packed (hi|lo<<16) u32 per element (Q plane pre-scaled by C).
// ---------------------------------------------------------------------------
__global__ __launch_bounds__(384) void qkv_kernel(
    const float* __restrict__ X, const float* __restrict__ STE,
    const uint4* __restrict__ WfH, const uint4* __restrict__ WfL,
    const float* __restrict__ b7, const float* __restrict__ b8,
    const float* __restrict__ b9,
    float* __restrict__ qkv)
{
    __shared__ float Xs[32][132];  // 16.9 KB raw [X|STE] rows (pad vs conflicts)
    __shared__ uint4 aH[512];      // 8 KB: A_hi frags, entry = c*64 + hh*32 + l31
    __shared__ uint4 aL[512];      // 8 KB: A_lo frags

    const int tid  = threadIdx.x;
    const int l31  = tid & 31;
    const int hh   = (tid >> 5) & 1;
    const int wave = tid >> 6;              // 0..5
    const int w    = wave >> 1;             // 0,1,2 -> W7,W8,W9
    const int tt   = wave & 1;              // column half
    const size_t blockrow = (size_t)blockIdx.x * 32;

    // Phase 1: coalesced raw stage. 1024 float4s: row = e>>5, seg = e&31.
    for (int e = tid; e < 1024; e += 384) {
        const int row = e >> 5;
        const int seg = e & 31;
        const float* src = (seg < 16) ? X : STE;
        const float4 v = *(const float4*)(src + (blockrow + row) * 64 + (seg & 15) * 4);
        float* dst = &Xs[row][seg * 4];
        dst[0] = v.x; dst[1] = v.y; dst[2] = v.z; dst[3] = v.w;
    }
    __syncthreads();

    // Phase 2: build split frags from LDS (split once, consumed by 6 waves).
    for (int e = tid; e < 512; e += 384) {
        const int el  = e & 31;
        const int ehh = (e >> 5) & 1;
        const int ec  = e >> 6;
        const float* hp = &Xs[el][ec * 16 + ehh * 8];
        float av[8];
        #pragma unroll
        for (int j = 0; j < 8; ++j) av[j] = hp[j];
        uint4 hi, lo;
        split_pack8(av, &hi, &lo);
        aH[e] = hi;
        aL[e] = lo;
    }
    __syncthreads();

    float16v accM, accC;
    #pragma unroll
    for (int i = 0; i < 16; ++i) { accM[i] = 0.f; accC[i] = 0.f; }

    #pragma unroll
    for (int c = 0; c < 8; ++c) {
        const uint4 ahi = aH[c * 64 + hh * 32 + l31];
        const uint4 alo = aL[c * 64 + hh * 32 + l31];
        const int ei = w * 1024 + c * 128 + hh * 64 + tt * 32 + l31;
        const uint4 bh = WfH[ei];
        const uint4 bl = WfL[ei];
        accM = __builtin_amdgcn_mfma_f32_32x32x16_bf16(
            as_s8(ahi), as_s8(bh), accM, 0, 0, 0);
        accC = __builtin_amdgcn_mfma_f32_32x32x16_bf16(
            as_s8(alo), as_s8(bh), accC, 0, 0, 0);
        accC = __builtin_amdgcn_mfma_f32_32x32x16_bf16(
            as_s8(ahi), as_s8(bl), accC, 0, 0, 0);
    }

    const float* bv = (w == 0) ? b7 : (w == 1) ? b8 : b9;
    // Head-major store: col = tt*32+l31 = head*8 + d.
    const int head = tt * 4 + (l31 >> 3);
    const int d    = l31 & 7;
    const int col  = tt * 32 + l31;
    uint32_t* obase = (uint32_t*)qkv + (size_t)w * ((size_t)RTOT * DMODEL)
                      + (size_t)head * HPLANE;
    const float bias = bv[col];
    const float cs = (w == 0) ? 0.51012091684045906f : 1.0f;  // Q pre-scale
    #pragma unroll
    for (int r = 0; r < 16; r += 2) {
        const int rowC0 = (r & 3) + 8 * (r >> 2) + 4 * hh;
        const int rowC1 = ((r + 1) & 3) + 8 * ((r + 1) >> 2) + 4 * hh;
        const float v0 = fmaxf(accM[r]     + accC[r]     + bias, 0.f) * cs;
        const float v1 = fmaxf(accM[r + 1] + accC[r + 1] + bias, 0.f) * cs;
        uint32_t s0, s1;
        split_store_pair(v0, v1, &s0, &s1);
        obase[(blockrow + rowC0) * 8 + d] = s0;
        obase[(blockrow + rowC1) * 8 + d] = s1;
    }
}

// ---------------------------------------------------------------------------
// Kernel 2 (R23): attention, 768 x 1024 threads (R17 shape). Staging via
// perm-repack of packed split-u32 (R22). Epilogue now ALSO stores O as
// packed split-u32 (same RNE split of the same fp32 values proj used to
// compute itself) -> proj's phase-A split collapses to perm repacks.
// ---------------------------------------------------------------------------
__global__ __launch_bounds__(1024) void attn_kernel(
    const float* __restrict__ qkv, float* __restrict__ obuf)
{
    __shared__ uint4 ak1[16 * 32];    //  8.0 KB  k_hi
    __shared__ uint4 ak2p[16 * 33];   //  8.3 KB  k_lo | zero column
    __shared__ uint4 vfh[640];        // 10.0 KB  V_hi frags (+zero pad)
    __shared__ uint4 vfl[640];        // 10.0 KB  V_lo frags (+zero pad)

    const int tid  = threadIdx.x;
    const int lane = tid & 63;
    const int l31  = lane & 31;
    const int hh   = lane >> 5;
    const int qt   = tid >> 6;               // 0..15: this wave's q-tile
    const int head = blockIdx.x & 7;
    const int bt   = blockIdx.x >> 3;

    // Head-major base: plane 'head', rows bt*512..bt*512+511, 8 elems/row.
    const size_t hb = (size_t)head * HPLANE + (size_t)bt * (NSEQ * 8);
    const uint32_t* Qp = (const uint32_t*)qkv + QOFF + hb;
    const uint32_t* Kp = (const uint32_t*)qkv + KOFF + hb;
    const uint32_t* Vp = (const uint32_t*)qkv + VOFF + hb;

    const uint4 z4 = make_uint4(0, 0, 0, 0);

    // K staging: threads 0..511, contiguous 32B rows; perm-repack.
    if (tid < 512) {
        const int k = tid;
        const uint32_t* kr = Kp + (size_t)k * 8;
        const uint4 p0 = *(const uint4*)(kr);
        const uint4 p1 = *(const uint4*)(kr + 4);
        ak1[k] = hi4_of(p0, p1);
        ak2p[(k >> 5) * 33 + (k & 31)] = lo4_of(p0, p1);
    }
    if (tid < 16) ak2p[tid * 33 + 32] = z4;

    // V-frag build: threads 0..639 (global gather; perm-repack).
    if (tid < 640) {
        const int e = tid;
        if (e < 576) {
            int s  = e / 18;
            int r  = e % 18;
            int hv = r / 9;
            int n  = r % 9;
            uint32_t p[8];
            #pragma unroll
            for (int j = 0; j < 8; ++j) {
                int key = 16 * s + ((j < 4) ? (4 * hv + j) : (8 + 4 * hv + (j - 4)));
                p[j] = (n < 8) ? Vp[(size_t)key * 8 + n] : 0x00003F80u;  // split(1.0f)
            }
            vfh[e] = make_uint4(perm_hi(p[0], p[1]), perm_hi(p[2], p[3]),
                                perm_hi(p[4], p[5]), perm_hi(p[6], p[7]));
            vfl[e] = make_uint4(perm_lo(p[0], p[1]), perm_lo(p[2], p[3]),
                                perm_lo(p[4], p[5]), perm_lo(p[6], p[7]));
        } else {
            vfh[e] = z4;
            vfl[e] = z4;
        }
    }

    __syncthreads();

    const int idx2 = hh ? 32 : l31;        // zero column for hh=1 lanes

    float16v Z16;
    #pragma unroll
    for (int i = 0; i < 16; ++i) Z16[i] = 0.f;

    {
        // Q fragment: pre-scaled + pre-split in qkv; perm-repack only.
        const uint32_t* qp = Qp + (size_t)(qt * 32 + l31) * 8;
        const uint4 p0 = *(const uint4*)(qp);
        const uint4 p1 = *(const uint4*)(qp + 4);
        const uint4 qhi = hi4_of(p0, p1);
        const uint4 qlo = lo4_of(p0, p1);
        const uint4 bq1 = hh ? qlo : qhi;
        const uint4 bq2 = qhi;

        float16v O = Z16;

        // Prologue: S for c=0.
        float16v Sa, Sb;
        {
            const uint4 a1 = ak1[l31];
            const uint4 a2 = ak2p[idx2];
            Sa = __builtin_amdgcn_mfma_f32_32x32x16_bf16(as_s8(a1), as_s8(bq1), Z16, 0, 0, 0);
            Sa = __builtin_amdgcn_mfma_f32_32x32x16_bf16(as_s8(a2), as_s8(bq2), Sa, 0, 0, 0);
        }

        // One pipelined step: consume Scur (exp/pack-hi/O-MFMA) while issuing
        // the S-MFMAs for iteration cn into Snext.
#define ATTN_STEP(Scur, Snext, cc, cn)                                         \
        {                                                                      \
            const int vi0 = (4 * (cc) + hh) * 9;                               \
            const int vi1 = (4 * (cc) + 2 + hh) * 9;                           \
            const uint4 bh0 = vfh[vi0 + l31];                                  \
            const uint4 bl0 = vfl[vi0 + l31];                                  \
            const uint4 bh1 = vfh[vi1 + l31];                                  \
            const uint4 bl1 = vfl[vi1 + l31];                                  \
            const uint4 a1n = ak1[(cn) * 32 + l31];                            \
            const uint4 a2n = ak2p[(cn) * 33 + idx2];                          \
            Snext = __builtin_amdgcn_mfma_f32_32x32x16_bf16(                   \
                as_s8(a1n), as_s8(bq1), Z16, 0, 0, 0);                         \
            Snext = __builtin_amdgcn_mfma_f32_32x32x16_bf16(                   \
                as_s8(a2n), as_s8(bq2), Snext, 0, 0, 0);                       \
            _Pragma("unroll")                                                  \
            for (int i = 0; i < 16; ++i) Scur[i] = fast_exp2(Scur[i]);         \
            const uint4 ph0 = pack_hi8((const float*)&Scur);                   \
            const uint4 ph1 = pack_hi8(((const float*)&Scur) + 8);             \
            O = __builtin_amdgcn_mfma_f32_32x32x16_bf16(                       \
                as_s8(ph0), as_s8(bh0), O, 0, 0, 0);                           \
            O = __builtin_amdgcn_mfma_f32_32x32x16_bf16(                       \
                as_s8(ph0), as_s8(bl0), O, 0, 0, 0);                           \
            O = __builtin_amdgcn_mfma_f32_32x32x16_bf16(                       \
                as_s8(ph1), as_s8(bh1), O, 0, 0, 0);                           \
            O = __builtin_amdgcn_mfma_f32_32x32x16_bf16(                       \
                as_s8(ph1), as_s8(bl1), O, 0, 0, 0);                           \
        }

        for (int c = 0; c < 16; c += 2) {
            ATTN_STEP(Sa, Sb, c, c + 1);
            ATTN_STEP(Sb, Sa, c + 1, (c + 2) & 15);  // last prefetch discarded
        }
#undef ATTN_STEP

        // Epilogue: normalize, split-pack pairs, store packed u32 O.
        uint32_t* ob = (uint32_t*)obuf + hb;
        #pragma unroll
        for (int r = 0; r < 16; r += 2) {
            float ov0 = O[r];
            float den0 = __uint_as_float(
                __builtin_amdgcn_ds_swizzle(__float_as_uint(ov0), 0x100));
            float o0 = ov0 * fast_rcp(den0);
            float ov1 = O[r + 1];
            float den1 = __uint_as_float(
                __builtin_amdgcn_ds_swizzle(__float_as_uint(ov1), 0x100));
            float o1 = ov1 * fast_rcp(den1);
            uint32_t s0, s1;
            split_store_pair(o0, o1, &s0, &s1);
            if (l31 < 8) {
                const int row0 = (r & 3) + 8 * (r >> 2) + 4 * hh;
                ob[(size_t)(qt * 32 + row0) * 8 + l31] = s0;
                ob[(size_t)(qt * 32 + row0 + 1) * 8 + l31] = s1;
            }
        }
    }
}

// ---------------------------------------------------------------------------
// Kernel 3 (R23): fused projection; phase A now perm-repacks packed-u32
// obuf (was 4x split_pack8 = ~100 VALU/thread). Phase B unchanged.
// ---------------------------------------------------------------------------
__global__ __launch_bounds__(128) void proj_kernel(
    const float* __restrict__ obuf,
    const uint4* __restrict__ WfH, const uint4* __restrict__ WfL,
    const float* __restrict__ b10, const float* __restrict__ b11,
    float* __restrict__ out)
{
    __shared__ float Ts[32][84];

    const int tid  = threadIdx.x;
    const int lane = tid & 63;
    const int l31  = lane & 31;
    const int hh   = lane >> 5;
    const int tw   = tid >> 6;               // 0/1: column half this wave owns
    const size_t row = (size_t)blockIdx.x * 32 + l31;
    const size_t blockrow = (size_t)blockIdx.x * 32;

    float16v accM, accC;
    #pragma unroll
    for (int i = 0; i < 16; ++i) { accM[i] = 0.f; accC[i] = 0.f; }

    #pragma unroll
    for (int c = 0; c < 4; ++c) {
        // A-frag cols c*16+hh*8..+7 = head plane 2c+hh, contiguous row.
        const uint32_t* ap = (const uint32_t*)obuf
                             + (size_t)(2 * c + hh) * HPLANE + row * 8;
        const uint4 p0 = *(const uint4*)(ap);
        const uint4 p1 = *(const uint4*)(ap + 4);
        const uint4 ahi = hi4_of(p0, p1);
        const uint4 alo = lo4_of(p0, p1);

        const int ei = 3072 + c * 128 + hh * 64 + tw * 32 + l31;   // W10
        const uint4 bh = WfH[ei];
        const uint4 bl = WfL[ei];
        accM = __builtin_amdgcn_mfma_f32_32x32x16_bf16(
            as_s8(ahi), as_s8(bh), accM, 0, 0, 0);
        accC = __builtin_amdgcn_mfma_f32_32x32x16_bf16(
            as_s8(alo), as_s8(bh), accC, 0, 0, 0);
        accC = __builtin_amdgcn_mfma_f32_32x32x16_bf16(
            as_s8(ahi), as_s8(bl), accC, 0, 0, 0);
    }

    {
        const int col = tw * 32 + l31;
        const float bias = b10[col];
        #pragma unroll
        for (int r = 0; r < 16; ++r) {
            const int rowC = (r & 3) + 8 * (r >> 2) + 4 * hh;
            Ts[rowC][col] = fmaxf(accM[r] + accC[r] + bias, 0.f);
        }
    }
    __syncthreads();

    #pragma unroll
    for (int i = 0; i < 16; ++i) { accM[i] = 0.f; accC[i] = 0.f; }

    #pragma unroll
    for (int c = 0; c < 4; ++c) {
        const float* ap = &Ts[l31][c * 16 + hh * 8];
        float av[8];
        {
            float4 a0 = *(const float4*)(ap);
            float4 a1 = *(const float4*)(ap + 4);
            av[0] = a0.x; av[1] = a0.y; av[2] = a0.z; av[3] = a0.w;
            av[4] = a1.x; av[5] = a1.y; av[6] = a1.z; av[7] = a1.w;
        }
        uint4 ahi, alo;
        split_pack8(av, &ahi, &alo);

        const int ei = 3584 + c * 128 + hh * 64 + tw * 32 + l31;   // W11
        const uint4 bh = WfH[ei];
        const uint4 bl = WfL[ei];
        accM = __builtin_amdgcn_mfma_f32_32x32x16_bf16(
            as_s8(ahi), as_s8(bh), accM, 0, 0, 0);
        accC = __builtin_amdgcn_mfma_f32_32x32x16_bf16(
            as_s8(alo), as_s8(bh), accC, 0, 0, 0);
        accC = __builtin_amdgcn_mfma_f32_32x32x16_bf16(
            as_s8(ahi), as_s8(bl), accC, 0, 0, 0);
    }

    {
        const int col = tw * 32 + l31;
        const float bias = b11[col];
        #pragma unroll
        for (int r = 0; r < 16; ++r) {
            const int rowC = (r & 3) + 8 * (r >> 2) + 4 * hh;
            out[(blockrow + rowC) * 64 + col] = accM[r] + accC[r] + bias;
        }
    }
}

// ---------------------------------------------------------------------------
extern "C" void kernel_launch(void* const* d_in, const int* in_sizes, int n_in,
                              void* d_out, int out_size, void* d_ws, size_t ws_size,
                              hipStream_t stream)
{
    const float* X   = (const float*)d_in[0];
    const float* STE = (const float*)d_in[1];
    const float* W7  = (const float*)d_in[2];
    const float* b7  = (const float*)d_in[3];
    const float* W8  = (const float*)d_in[4];
    const float* b8  = (const float*)d_in[5];
    const float* W9  = (const float*)d_in[6];
    const float* b9  = (const float*)d_in[7];
    const float* W10 = (const float*)d_in[8];
    const float* b10 = (const float*)d_in[9];
    const float* W11 = (const float*)d_in[10];
    const float* b11 = (const float*)d_in[11];

    float* ws  = (float*)d_ws;   // Q | K | V | O | Wf
    float* out = (float*)d_out;

    uint4* WfH = (uint4*)(ws + WOFF);
    uint4* WfL = WfH + 4096;

    wprep_kernel<<<dim3(16), 256, 0, stream>>>(W7, W8, W9, W10, W11, WfH, WfL);
    qkv_kernel<<<dim3(RTOT / 32), 384, 0, stream>>>(X, STE, WfH, WfL, b7, b8, b9, ws);
    attn_kernel<<<dim3(BT * 8), 1024, 0, stream>>>(ws, ws + OOFF);
    proj_kernel<<<dim3(RTOT / 32), 128, 0, stream>>>(ws + OOFF, WfH, WfL, b10, b11, out);
}